// Round 16
// baseline (28.038 us; speedup 1.0000x reference)
//
#include <hip/hip_runtime.h>

#define NB_ 8
#define NA_ 120
#define NHALF 60
#define NNEI 119
#define NJ 60
#define NK 40
#define NRAD 43
#define NAP 21

#define OFF_RA 0
#define OFF_RB 103200
#define OFF_APA 206400
#define OFF_APB 3230400
#define OFF_D 6254400
#define OFF_END 6312000

typedef unsigned short u16;
typedef unsigned int u32;
typedef unsigned long long u64;

#if defined(__has_builtin)
#if __has_builtin(__builtin_amdgcn_exp2f)
#define FAST_EXP2(x) __builtin_amdgcn_exp2f(x)
#else
#define FAST_EXP2(x) exp2f(x)
#endif
#else
#define FAST_EXP2(x) exp2f(x)
#endif

__device__ __forceinline__ float bf2f(u16 u) { return __uint_as_float(((u32)u) << 16); }
__device__ __forceinline__ float cut8(float d) {
    return (d < 8.0f) ? 0.5f * (__cosf(d * 0.39269908169872414f) + 1.0f) : 0.0f;
}
__device__ __forceinline__ int ld_idx(const void* p, int i, int w64) {
    return w64 ? (int)((const long long*)p)[i] : ((const int*)p)[i];
}
__device__ __forceinline__ float ldf(const void* p, size_t i, int f32) {
    return f32 ? ((const float*)p)[i] : bf2f(((const u16*)p)[i]);
}
__device__ __forceinline__ int inset5(int v) {
    return (v == 1 || v == 6 || v == 7 || v == 8 || v == 9);
}
__device__ __forceinline__ int isBF1(u32 w) { return (w & 0xFFFFu) == 0x3F80u; }
__device__ __forceinline__ int isF321(u32 w) { return w == 0x3F800000u; }

// 960 blocks x 320 threads (5 waves), ~24.3 KB LDS.
// P: per-wave probe  A: stage (ballot-rank wave2, dists on idle threads)
// B: bf16-packed E/S at sorted pos  C: 2x-unrolled dual-chain accumulation
// stage sacc16 -> float4 copy (+concurrent radial partials) -> radial final.
__global__ __launch_bounds__(320, 6) void k_fused(
    const u16* __restrict__ pos, const u16* __restrict__ cellw,
    const u16* __restrict__ coff, const u16* __restrict__ noi,
    const u16* __restrict__ coi, const u16* __restrict__ zww,
    const void* __restrict__ Zv, const void* __restrict__ nbrv,
    const u16* __restrict__ nmw, const void* __restrict__ p9,
    const void* __restrict__ p10, const void* __restrict__ p11,
    const void* __restrict__ p12, const void* __restrict__ p13,
    const void* __restrict__ p14, const void* __restrict__ p15,
    int hostN, float* __restrict__ out) {

    const int b = blockIdx.x / NA_;
    const int a = blockIdx.x % NA_;
    const int tid = threadIdx.x;
    const int lane = tid & 63;
    const int wzi = tid >> 6;

    __shared__ float sj[NJ * 6];
    __shared__ float sk[NK * 6];
    __shared__ float szval[NK];
    __shared__ int srnk[NK];
    __shared__ int sbnd[6];
    __shared__ float scg2[NAP];
    __shared__ float sd[NNEI];
    __shared__ float swzl[NNEI * 5];
    union UnionT {
        u32 scES[NJ * 41];             //  9840 B: (bf16 S)<<16 | (bf16 E)
        u16 sacc16[NJ * 105];          // 12600 B
        u32 sacc32[(NJ * 105) / 2];
    };
    __shared__ UnionT U;
    __shared__ float dpart[NRAD * 7 * 5];

    // ---- Phase P: per-wave probe (wave-uniform, NO barrier) ----
    int t10a = ((const int*)p10)[lane * 7];
    int t10e = ((const int*)p10)[2 * (lane * 3)];
    int t10o = ((const int*)p10)[2 * (lane * 3) + 1];
    int p12e = ((const int*)p12)[2 * (lane & 31)];
    int p12o = ((const int*)p12)[2 * (lane & 31) + 1];
    int z32 = ((const int*)Zv)[lane * 15];
    int z64e = ((const int*)Zv)[2 * (lane * 7)];
    int z64o = ((const int*)Zv)[2 * (lane * 7) + 1];
    float pv = bf2f(pos[lane * 44]);
    u32 xw = 0;
    if (lane == 0) xw = ((const u32*)cellw)[0];
    else if (lane == 1) xw = ((const u32*)zww)[2];
    else if (lane == 2) xw = ((const u32*)zww)[5];
    else if (lane == 3) xw = ((const u32*)nmw)[0];
    else if (lane == 4) xw = ((const u32*)p11)[0];
    else if (lane == 5) xw = ((const u32*)p13)[0];
    else if (lane == 6) xw = ((const u32*)p15)[0];

    u64 b1 = __ballot(inset5(t10a));
    u64 b2 = __ballot(inset5(t10e) && t10o == 0);
    u64 b3 = __ballot((lane < 32) ? (p12o == 0 && (u32)p12e < 120u) : 1);
    u64 b4 = __ballot(inset5(z32));
    u64 b5 = __ballot(inset5(z64e) && z64o == 0);
    u64 b6 = __ballot((pv == pv) && fabsf(pv) < 16.0f);
    u32 w0 = __shfl(xw, 0), w1 = __shfl(xw, 1), w2 = __shfl(xw, 2);
    u32 w3 = __shfl(xw, 3), w4 = __shfl(xw, 4), w5 = __shfl(xw, 5);
    u32 w6 = __shfl(xw, 6);

    const int L16 = (~b1 == 0ull) || (~b2 == 0ull);
    const int w64 = (~b3 == 0ull);
    const int zOK = w64 ? (~b5 == 0ull) : (~b4 == 0ull);
    const int pcnt = __popcll(b6);
    const int pF = (pcnt < 56);
    const int posOK = (pcnt >= 56) || (pcnt < 48);
    const int cellBF = ((w0 & 0xFFFFu) == 0x4140u), cellF32b = (w0 == 0x41400000u);
    const int cF = (cellF32b && !cellBF);
    const int zwBF = ((w1 >> 16) == 0x3F80u), zwF32b = (w2 == 0x3F800000u);
    const int zF = (zwF32b && !zwBF);
    const int nmBF = isBF1(w3), nmF32b = isF321(w3);
    const int nmF = (nmF32b && !nmBF);
    const u32 pmw = L16 ? w5 : w4;
    const u32 niw = L16 ? w6 : w5;
    const int pmBF = isBF1(pmw), pmF32b = isF321(pmw);
    const int pmF = (pmF32b && !pmBF);
    const int niBF = isBF1(niw), niF32b = isF321(niw);
    const int niF = (niF32b && !niBF);
    const int masksOK = (nmBF || nmF32b) && (pmBF || pmF32b) && (niBF || niF32b);
    const int layoutOK = ((hostN != 14) && (hostN != 16)) || ((hostN == 16) == (L16 != 0));
    const int armed = !((cellBF || cellF32b) && (zwBF || zwF32b) && masksOK &&
                        zOK && posOK && layoutOK);
    const int mbits = (L16 ? 1 : 0) | (pF << 1) | (cF << 2) | (zF << 3) |
                      (nmF << 4) | (pmF << 5) | (niF << 6) | (w64 << 7);
    const int ebits = ((cellBF || cellF32b) ? 1 : 0) | ((zwBF || zwF32b) << 1) |
                      (masksOK << 2) | (zOK << 3);

    const void* idxj = L16 ? p11 : p9;
    const void* idxk = L16 ? p12 : p10;
    const void* pmv  = L16 ? p13 : p11;
    const void* nint = L16 ? p14 : p12;
    const void* nimv = L16 ? p15 : p13;

    // ---- pmask register prefetch ----
    float pmr[8];
    {
        size_t pb = (size_t)(b * NA_ + a) * (NJ * NK);
#pragma unroll
        for (int s = 0; s < 8; ++s) {
            int tt = tid + s * 320;
            if (tt < NJ * NK) pmr[s] = ldf(pmv, pb + tt, pmF);
        }
    }

    float C[9];
#pragma unroll
    for (int i = 0; i < 9; ++i) C[i] = ldf(cellw, b * 9 + i, cF);
    const float ix = ldf(pos, (b * NA_ + a) * 3 + 0, pF);
    const float iy = ldf(pos, (b * NA_ + a) * 3 + 1, pF);
    const float iz = ldf(pos, (b * NA_ + a) * 3 + 2, pF);

    // ---- Phase A ----
    if (tid < NJ) {                          // wave 0: j geometry
        int j = tid;
        int id = ld_idx(idxj, (b * NA_ + a) * NJ + j, w64);
        id = min(max(id, 0), NA_ - 1);
        size_t ob = (size_t)((b * NA_ + a) * NJ + j) * 3;
        float o0 = bf2f(noi[ob]), o1 = bf2f(noi[ob + 1]), o2 = bf2f(noi[ob + 2]);
        float jx = ldf(pos, (b * NA_ + id) * 3 + 0, pF) + o0 * C[0] + o1 * C[3] + o2 * C[6];
        float jy = ldf(pos, (b * NA_ + id) * 3 + 1, pF) + o0 * C[1] + o1 * C[4] + o2 * C[7];
        float jz = ldf(pos, (b * NA_ + id) * 3 + 2, pF) + o0 * C[2] + o1 * C[5] + o2 * C[8];
        float dx = jx - ix, dy = jy - iy, dz = jz - iz;
        float rij2 = fmaxf(dx * dx + dy * dy + dz * dz, 1e-12f);
        float rij = sqrtf(rij2);
        sj[j * 6 + 0] = jx; sj[j * 6 + 1] = jy; sj[j * 6 + 2] = jz;
        sj[j * 6 + 3] = rij2; sj[j * 6 + 4] = 0.5f / rij; sj[j * 6 + 5] = cut8(rij);
    }
    if (tid >= 64 && tid < 64 + NK) {        // wave 1 lanes 0-39: k geometry
        int k = tid - 64;
        int id = ld_idx(idxk, (b * NA_ + a) * NK + k, w64);
        id = min(max(id, 0), NA_ - 1);
        size_t ob = (size_t)((b * NA_ + a) * NK + k) * 3;
        float o0 = bf2f(coi[ob]), o1 = bf2f(coi[ob + 1]), o2 = bf2f(coi[ob + 2]);
        float kx = ldf(pos, (b * NA_ + id) * 3 + 0, pF) + o0 * C[0] + o1 * C[3] + o2 * C[6];
        float ky = ldf(pos, (b * NA_ + id) * 3 + 1, pF) + o0 * C[1] + o1 * C[4] + o2 * C[7];
        float kz = ldf(pos, (b * NA_ + id) * 3 + 2, pF) + o0 * C[2] + o1 * C[5] + o2 * C[8];
        float dx = kx - ix, dy = ky - iy, dz = kz - iz;
        float rik2 = fmaxf(dx * dx + dy * dy + dz * dz, 1e-12f);
        float rik = sqrtf(rik2);
        sk[k * 6 + 0] = kx; sk[k * 6 + 1] = ky; sk[k * 6 + 2] = kz;
        sk[k * 6 + 3] = rik2; sk[k * 6 + 4] = 1.0f / rik; sk[k * 6 + 5] = cut8(rik);
    }
    if (wzi == 2) {                          // wave 2: classes + ballot-rank + scg2
        int cls = 9;
        if (lane < NK) {
            int k = lane;
            int id = ld_idx(idxk, (b * NA_ + a) * NK + k, w64);
            id = min(max(id, 0), NA_ - 1);
            int zi = ld_idx(Zv, b * NA_ + id, w64);
            zi = min(max(zi, 0), 9);
            float z0 = ldf(zww, zi * 5 + 0, zF), z1 = ldf(zww, zi * 5 + 1, zF);
            float z2 = ldf(zww, zi * 5 + 2, zF), z3 = ldf(zww, zi * 5 + 3, zF);
            float z4 = ldf(zww, zi * 5 + 4, zF);
            cls = (z0 != 0.0f) ? 0 : ((z1 != 0.0f) ? 1 : ((z2 != 0.0f) ? 2 :
                  ((z3 != 0.0f) ? 3 : ((z4 != 0.0f) ? 4 : 5))));
            szval[k] = z0 + z1 + z2 + z3 + z4;
        }
        int pre = 0;
        u64 mybal = 0;
        int cnts[6];
#pragma unroll
        for (int c = 0; c < 6; ++c) {
            u64 blc = __ballot(cls == c);
            cnts[c] = __popcll(blc);
            pre += (c < cls) ? cnts[c] : 0;
            mybal = (c == cls) ? blc : mybal;
        }
        if (lane < NK) {
            u64 ltm = (1ull << lane) - 1ull;
            srnk[lane] = pre + __popcll(mybal & ltm);
        }
        if (lane < 6) {
            int cnt = 0;
#pragma unroll
            for (int c2 = 0; c2 < 5; ++c2) cnt += (c2 < lane) ? cnts[c2] : 0;
            sbnd[lane] = cnt;
        }
        if (lane >= 40 && lane < 40 + NAP) {
            float og = -1.0f + 0.1f * (float)(lane - 40);
            scg2[lane - 40] = FAST_EXP2(-36.06737602222409f * og * og);
        }
    }
    if (tid >= 201) {                        // waves 3-4: radial staging
        int n = tid - 201;
        int id = ld_idx(nbrv, (b * NA_ + a) * NNEI + n, w64);
        id = min(max(id, 0), NA_ - 1);
        size_t ob = (size_t)((b * NA_ + a) * NNEI + n) * 3;
        float o0 = bf2f(coff[ob]), o1 = bf2f(coff[ob + 1]), o2 = bf2f(coff[ob + 2]);
        float vx = ldf(pos, (b * NA_ + id) * 3 + 0, pF) + o0 * C[0] + o1 * C[3] + o2 * C[6] - ix;
        float vy = ldf(pos, (b * NA_ + id) * 3 + 1, pF) + o0 * C[1] + o1 * C[4] + o2 * C[7] - iy;
        float vz = ldf(pos, (b * NA_ + id) * 3 + 2, pF) + o0 * C[2] + o1 * C[5] + o2 * C[8] - iz;
        float d = sqrtf(fmaxf(vx * vx + vy * vy + vz * vz, 1e-12f));
        float m = ldf(nmw, (b * NA_ + a) * NNEI + n, nmF);
        float dm = (m != 0.0f) ? d : 0.0f;
        float w = cut8(dm) * m;
        int zi = ld_idx(Zv, b * NA_ + id, w64);
        zi = min(max(zi, 0), 9);
        sd[n] = dm;
#pragma unroll
        for (int e = 0; e < 5; ++e) swzl[n * 5 + e] = w * ldf(zww, zi * 5 + e, zF);
    }
    // ---- dists on idle threads (tids 104-127, 60-63, 189-190) ----
    {
        int ji = -1;
        if (tid >= 104 && tid < 128) ji = tid - 104;
        else if (tid >= 60 && tid < 64) ji = tid - 36;
        else if (tid >= 189 && tid < 191) ji = tid - 161;
        if (ji >= 0) {
            const int ad = (a < NHALF) ? a : (a - NHALF);
            const int j = ((a < NHALF) ? 0 : 30) + ji;
            int id = ld_idx(nint, (b * NA_ + ad) * NJ + j, w64);
            id = min(max(id, 0), NA_ - 1);
            size_t ob = (size_t)((b * NA_ + ad) * NJ + j) * 3;
            float o0 = bf2f(noi[ob]), o1 = bf2f(noi[ob + 1]), o2 = bf2f(noi[ob + 2]);
            float cx = ldf(pos, (b * NA_ + ad) * 3 + 0, pF);
            float cy = ldf(pos, (b * NA_ + ad) * 3 + 1, pF);
            float cz = ldf(pos, (b * NA_ + ad) * 3 + 2, pF);
            float vx = ldf(pos, (b * NA_ + id) * 3 + 0, pF) + o0 * C[0] + o1 * C[3] + o2 * C[6] - cx;
            float vy = ldf(pos, (b * NA_ + id) * 3 + 1, pF) + o0 * C[1] + o1 * C[4] + o2 * C[7] - cy;
            float vz = ldf(pos, (b * NA_ + id) * 3 + 2, pF) + o0 * C[2] + o1 * C[5] + o2 * C[8] - cz;
            float d = sqrtf(fmaxf(vx * vx + vy * vy + vz * vz, 1e-12f));
            float m = ldf(nimv, (b * NA_ + ad) * NJ + j, niF);
            float pd = (m != 0.0f) ? d : 1.0f;
            float fc = (pd < 9.0f) ? 0.5f * (cosf(pd * 0.3490658503988659f) + 1.0f) : 0.0f;
            float v0 = pd * fc;
            float v1 = fc / pd;
            v0 = (v0 == v0) ? v0 : 0.0f;
            v1 = (v1 == v1) ? v1 : 0.0f;
            int w0i = OFF_D + ((b * NHALF + ad) * NJ + j) * 2;
            if (w0i >= OFF_D && w0i + 1 < OFF_END) {
                out[w0i + 0] = v0;
                out[w0i + 1] = v1;
            }
            if (ji == 0 && b == 0 && a == 0 && armed)
                out[OFF_D] = ldexpf(1.0f + (float)mbits / 256.0f, 30 + ebits);
        }
    }
    __syncthreads();   // bar1

    // ---- Phase B: bf16-packed E/S at SORTED positions ----
    {
#pragma unroll
        for (int s = 0; s < 8; ++s) {
            int tt = tid + s * 320;
            if (tt < NJ * NK) {
                int j = tt / NK, k = tt - j * NK;
                float jx = sj[j * 6 + 0], jy = sj[j * 6 + 1], jz = sj[j * 6 + 2];
                float rij2 = sj[j * 6 + 3], aj = sj[j * 6 + 4], fcj = sj[j * 6 + 5];
                float kx = sk[k * 6 + 0], ky = sk[k * 6 + 1], kz = sk[k * 6 + 2];
                float rik2 = sk[k * 6 + 3], inv = sk[k * 6 + 4], fck = sk[k * 6 + 5];
                float ddx = kx - jx, ddy = ky - jy, ddz = kz - jz;
                float rjk2 = fmaxf(ddx * ddx + ddy * ddy + ddz * ddz, 1e-12f);
                float cth = (rij2 + rik2 - rjk2) * aj * inv;
                cth = fminf(fmaxf(cth, -1.0f), 1.0f);
                float wb = fcj * fck * pmr[s] * szval[k];
                float t0 = -36.06737602222409f * cth * cth;
                float E = FAST_EXP2(7.213475204444817f * cth);
                float S = wb * FAST_EXP2(t0 - 72.13475204444817f * cth);
                int rnk = srnk[k];
                U.scES[j * 41 + rnk] = (__float_as_uint(S) & 0xFFFF0000u) |
                                       (__float_as_uint(E) >> 16);
            }
        }
    }
    __syncthreads();   // bar2

    // ---- Phase C: 2x-unrolled dual-chain class-segmented accumulation ----
    float acc[5][5];
#pragma unroll
    for (int c = 0; c < 5; ++c)
#pragma unroll
        for (int t = 0; t < 5; ++t) acc[c][t] = 0.0f;
    const int gbase = wzi * 4;
    if (lane < NJ) {
        const int rowc = lane * 41;
#pragma unroll
        for (int c = 0; c < 5; ++c) {
            int ppos = (c == 0) ? 0 : sbnd[c];
            const int pend = sbnd[c + 1];
            for (; ppos + 1 < pend; ppos += 2) {   // dual independent chains
                u32 pk0 = U.scES[rowc + ppos];
                u32 pk1 = U.scES[rowc + ppos + 1];
                float E0 = __uint_as_float(pk0 << 16);
                float S0 = __uint_as_float(pk0 & 0xFFFF0000u);
                float E1 = __uint_as_float(pk1 << 16);
                float S1 = __uint_as_float(pk1 & 0xFFFF0000u);
                float s0, s1;
                if (wzi == 0) { s0 = S0; s1 = S1; }
                else {
                    float E0_2 = E0 * E0, E0_4 = E0_2 * E0_2;
                    float E1_2 = E1 * E1, E1_4 = E1_2 * E1_2;
                    if (wzi == 1) { s0 = S0 * E0_4; s1 = S1 * E1_4; }
                    else if (wzi == 2) { s0 = S0 * (E0_4 * E0_4); s1 = S1 * (E1_4 * E1_4); }
                    else if (wzi == 3) { s0 = S0 * (E0_4 * E0_4) * E0_4; s1 = S1 * (E1_4 * E1_4) * E1_4; }
                    else { float E0_8 = E0_4 * E0_4, E1_8 = E1_4 * E1_4;
                           s0 = S0 * (E0_8 * E0_8); s1 = S1 * (E1_8 * E1_8); }
                }
                acc[c][0] += s0; acc[c][0] += s1; s0 *= E0; s1 *= E1;
                acc[c][1] += s0; acc[c][1] += s1; s0 *= E0; s1 *= E1;
                acc[c][2] += s0; acc[c][2] += s1; s0 *= E0; s1 *= E1;
                acc[c][3] += s0; acc[c][3] += s1; s0 *= E0; s1 *= E1;
                acc[c][4] += s0; acc[c][4] += s1;
            }
            if (ppos < pend) {                     // tail
                u32 pk = U.scES[rowc + ppos];
                float E = __uint_as_float(pk << 16);
                float S = __uint_as_float(pk & 0xFFFF0000u);
                float seed;
                if (wzi == 0) seed = S;
                else {
                    float E2 = E * E, E4 = E2 * E2;
                    if (wzi == 1) seed = S * E4;
                    else if (wzi == 2) seed = S * (E4 * E4);
                    else if (wzi == 3) seed = S * (E4 * E4) * E4;
                    else { float E8 = E4 * E4; seed = S * (E8 * E8); }
                }
                acc[c][0] += seed; seed *= E;
                acc[c][1] += seed; seed *= E;
                acc[c][2] += seed; seed *= E;
                acc[c][3] += seed; seed *= E;
                acc[c][4] += seed;
            }
        }
    }
    __syncthreads();   // bar3 (scES dead -> sacc16)

    if (lane < NJ) {
        float cgs[5];
#pragma unroll
        for (int t = 0; t < 5; ++t) cgs[t] = scg2[gbase + t];
        const int base = lane * 105;
#pragma unroll
        for (int c = 0; c < 5; ++c) {
#pragma unroll
            for (int t = 0; t < 5; ++t) {
                if (wzi == 0 || t > 0)
                    U.sacc16[base + c * 21 + gbase + t] =
                        (u16)(__float_as_uint(acc[c][t] * cgs[t]) >> 16);
            }
        }
    }
    __syncthreads();   // bar4

    // ---- coalesced AP copy (unpack bf16 -> float4) + concurrent radial partials ----
    {
        size_t ob2base = (a < NHALF)
            ? (size_t)OFF_APA + (size_t)(b * NHALF + a) * 6300
            : (size_t)OFF_APB + (size_t)(b * NHALF + (a - NHALF)) * 6300;
        for (int i4 = tid; i4 < 1575; i4 += 320) {
            size_t w = ob2base + (size_t)i4 * 4;
            if (w + 4 <= OFF_D) {
                u32 lo = U.sacc32[i4 * 2];
                u32 hi = U.sacc32[i4 * 2 + 1];
                float4 v;
                v.x = __uint_as_float(lo << 16);
                v.y = __uint_as_float(lo & 0xFFFF0000u);
                v.z = __uint_as_float(hi << 16);
                v.w = __uint_as_float(hi & 0xFFFF0000u);
                *(float4*)&out[w] = v;
            }
        }
    }
    if (tid < NRAD * 7) {
        int r = tid / 7, s = tid - r * 7;
        float o = 0.8f + 0.1f * (float)r;
        float ac0 = 0.f, ac1 = 0.f, ac2 = 0.f, ac3 = 0.f, ac4 = 0.f;
        int n0 = s * 17;
        for (int n = n0; n < n0 + 17; ++n) {
            float dd = sd[n] - o;
            float q = FAST_EXP2(-144.26950408889635f * dd * dd);
            ac0 = fmaf(q, swzl[n * 5 + 0], ac0);
            ac1 = fmaf(q, swzl[n * 5 + 1], ac1);
            ac2 = fmaf(q, swzl[n * 5 + 2], ac2);
            ac3 = fmaf(q, swzl[n * 5 + 3], ac3);
            ac4 = fmaf(q, swzl[n * 5 + 4], ac4);
        }
        int pbase = (r * 7 + s) * 5;
        dpart[pbase + 0] = ac0; dpart[pbase + 1] = ac1; dpart[pbase + 2] = ac2;
        dpart[pbase + 3] = ac3; dpart[pbase + 4] = ac4;
    }
    __syncthreads();   // bar5

    if (tid < 5 * NRAD) {
        int e = tid / NRAD, r = tid - e * NRAD;
        float s7 = 0.f;
#pragma unroll
        for (int s = 0; s < 7; ++s) s7 += dpart[(r * 7 + s) * 5 + e];
        int base = (a < NHALF) ? (OFF_RA + (b * NHALF + a) * (5 * NRAD))
                               : (OFF_RB + (b * NHALF + (a - NHALF)) * (5 * NRAD));
        int widx = base + tid;
        if (widx < OFF_APA) out[widx] = s7;
    }
}

extern "C" void kernel_launch(void* const* d_in, const int* in_sizes, int n_in,
                              void* d_out, int out_size, void* d_ws, size_t ws_size,
                              hipStream_t stream) {
    const u16* pos   = (const u16*)d_in[0];
    const u16* cellw = (const u16*)d_in[1];
    const u16* coff  = (const u16*)d_in[2];
    const u16* noi   = (const u16*)d_in[3];
    const u16* coi   = (const u16*)d_in[4];
    const u16* zww   = (const u16*)d_in[5];
    const void* Zv   = d_in[6];
    const void* nbrv = d_in[7];
    const u16* nmw   = (const u16*)d_in[8];
    const void* p9  = d_in[9];
    const void* p10 = d_in[10];
    const void* p11 = d_in[11];
    const void* p12 = d_in[12];
    const void* p13 = d_in[13];
    const void* p14 = (n_in >= 15) ? d_in[14] : d_in[13];
    const void* p15 = (n_in >= 16) ? d_in[15] : d_in[13];
    float* out = (float*)d_out;

    k_fused<<<NB_ * NA_, 320, 0, stream>>>(pos, cellw, coff, noi, coi, zww, Zv,
                                           nbrv, nmw, p9, p10, p11, p12, p13,
                                           p14, p15, n_in, out);
}

// Round 17
// 27.505 us; speedup vs baseline: 1.0194x; 1.0194x over previous
//
#include <hip/hip_runtime.h>

#define NB_ 8
#define NA_ 120
#define NHALF 60
#define NNEI 119
#define NJ 60
#define NK 40
#define NRAD 43
#define NAP 21

#define OFF_RA 0
#define OFF_RB 103200
#define OFF_APA 206400
#define OFF_APB 3230400
#define OFF_D 6254400
#define OFF_END 6312000

typedef unsigned short u16;
typedef unsigned int u32;
typedef unsigned long long u64;

#if defined(__has_builtin)
#if __has_builtin(__builtin_amdgcn_exp2f)
#define FAST_EXP2(x) __builtin_amdgcn_exp2f(x)
#else
#define FAST_EXP2(x) exp2f(x)
#endif
#else
#define FAST_EXP2(x) exp2f(x)
#endif

__device__ __forceinline__ float bf2f(u16 u) { return __uint_as_float(((u32)u) << 16); }
__device__ __forceinline__ float cut8(float d) {
    return (d < 8.0f) ? 0.5f * (__cosf(d * 0.39269908169872414f) + 1.0f) : 0.0f;
}
__device__ __forceinline__ int ld_idx(const void* p, int i, int w64) {
    return w64 ? (int)((const long long*)p)[i] : ((const int*)p)[i];
}
__device__ __forceinline__ float ldf(const void* p, size_t i, int f32) {
    return f32 ? ((const float*)p)[i] : bf2f(((const u16*)p)[i]);
}
__device__ __forceinline__ int inset5(int v) {
    return (v == 1 || v == 6 || v == 7 || v == 8 || v == 9);
}
__device__ __forceinline__ int isBF1(u32 w) { return (w & 0xFFFFu) == 0x3F80u; }
__device__ __forceinline__ int isF321(u32 w) { return w == 0x3F800000u; }

// 960 blocks x 320 threads (5 waves), ~24.3 KB LDS -> 6 blocks/CU (30 waves).
// P: per-wave probe  A: stage (ballot-rank on wave2, dists on idle threads)
// B: bf16-packed E/S at sorted pos  C: linear chained accum (1 LDS read/k)
// stage sacc16 -> float4 copy (+concurrent radial partials) -> radial final.
// 5 barriers total.  [round-15 best variant, reverted from r16's neutral unroll]
__global__ __launch_bounds__(320, 7) void k_fused(
    const u16* __restrict__ pos, const u16* __restrict__ cellw,
    const u16* __restrict__ coff, const u16* __restrict__ noi,
    const u16* __restrict__ coi, const u16* __restrict__ zww,
    const void* __restrict__ Zv, const void* __restrict__ nbrv,
    const u16* __restrict__ nmw, const void* __restrict__ p9,
    const void* __restrict__ p10, const void* __restrict__ p11,
    const void* __restrict__ p12, const void* __restrict__ p13,
    const void* __restrict__ p14, const void* __restrict__ p15,
    int hostN, float* __restrict__ out) {

    const int b = blockIdx.x / NA_;
    const int a = blockIdx.x % NA_;
    const int tid = threadIdx.x;
    const int lane = tid & 63;
    const int wzi = tid >> 6;

    __shared__ float sj[NJ * 6];       // 1440 B
    __shared__ float sk[NK * 6];       //  960 B
    __shared__ float szval[NK];        //  160 B
    __shared__ int srnk[NK];           //  160 B
    __shared__ int sbnd[6];            //   24 B
    __shared__ float scg2[NAP];        //   84 B
    __shared__ float sd[NNEI];         //  476 B
    __shared__ float swzl[NNEI * 5];   // 2380 B
    union UnionT {
        u32 scES[NJ * 41];             //  9840 B: (bf16 S)<<16 | (bf16 E)
        u16 sacc16[NJ * 105];          // 12600 B
        u32 sacc32[(NJ * 105) / 2];    // alias view
    };
    __shared__ UnionT U;               // 12600 B
    __shared__ float dpart[NRAD * 7 * 5];  // 6020 B (separate: overlaps copy)

    // ---- Phase P: per-wave probe (wave-uniform, NO barrier) ----
    int t10a = ((const int*)p10)[lane * 7];
    int t10e = ((const int*)p10)[2 * (lane * 3)];
    int t10o = ((const int*)p10)[2 * (lane * 3) + 1];
    int p12e = ((const int*)p12)[2 * (lane & 31)];
    int p12o = ((const int*)p12)[2 * (lane & 31) + 1];
    int z32 = ((const int*)Zv)[lane * 15];
    int z64e = ((const int*)Zv)[2 * (lane * 7)];
    int z64o = ((const int*)Zv)[2 * (lane * 7) + 1];
    float pv = bf2f(pos[lane * 44]);
    u32 xw = 0;
    if (lane == 0) xw = ((const u32*)cellw)[0];
    else if (lane == 1) xw = ((const u32*)zww)[2];
    else if (lane == 2) xw = ((const u32*)zww)[5];
    else if (lane == 3) xw = ((const u32*)nmw)[0];
    else if (lane == 4) xw = ((const u32*)p11)[0];
    else if (lane == 5) xw = ((const u32*)p13)[0];
    else if (lane == 6) xw = ((const u32*)p15)[0];

    u64 b1 = __ballot(inset5(t10a));
    u64 b2 = __ballot(inset5(t10e) && t10o == 0);
    u64 b3 = __ballot((lane < 32) ? (p12o == 0 && (u32)p12e < 120u) : 1);
    u64 b4 = __ballot(inset5(z32));
    u64 b5 = __ballot(inset5(z64e) && z64o == 0);
    u64 b6 = __ballot((pv == pv) && fabsf(pv) < 16.0f);
    u32 w0 = __shfl(xw, 0), w1 = __shfl(xw, 1), w2 = __shfl(xw, 2);
    u32 w3 = __shfl(xw, 3), w4 = __shfl(xw, 4), w5 = __shfl(xw, 5);
    u32 w6 = __shfl(xw, 6);

    const int L16 = (~b1 == 0ull) || (~b2 == 0ull);
    const int w64 = (~b3 == 0ull);
    const int zOK = w64 ? (~b5 == 0ull) : (~b4 == 0ull);
    const int pcnt = __popcll(b6);
    const int pF = (pcnt < 56);
    const int posOK = (pcnt >= 56) || (pcnt < 48);
    const int cellBF = ((w0 & 0xFFFFu) == 0x4140u), cellF32b = (w0 == 0x41400000u);
    const int cF = (cellF32b && !cellBF);
    const int zwBF = ((w1 >> 16) == 0x3F80u), zwF32b = (w2 == 0x3F800000u);
    const int zF = (zwF32b && !zwBF);
    const int nmBF = isBF1(w3), nmF32b = isF321(w3);
    const int nmF = (nmF32b && !nmBF);
    const u32 pmw = L16 ? w5 : w4;
    const u32 niw = L16 ? w6 : w5;
    const int pmBF = isBF1(pmw), pmF32b = isF321(pmw);
    const int pmF = (pmF32b && !pmBF);
    const int niBF = isBF1(niw), niF32b = isF321(niw);
    const int niF = (niF32b && !niBF);
    const int masksOK = (nmBF || nmF32b) && (pmBF || pmF32b) && (niBF || niF32b);
    const int layoutOK = ((hostN != 14) && (hostN != 16)) || ((hostN == 16) == (L16 != 0));
    const int armed = !((cellBF || cellF32b) && (zwBF || zwF32b) && masksOK &&
                        zOK && posOK && layoutOK);
    const int mbits = (L16 ? 1 : 0) | (pF << 1) | (cF << 2) | (zF << 3) |
                      (nmF << 4) | (pmF << 5) | (niF << 6) | (w64 << 7);
    const int ebits = ((cellBF || cellF32b) ? 1 : 0) | ((zwBF || zwF32b) << 1) |
                      (masksOK << 2) | (zOK << 3);

    const void* idxj = L16 ? p11 : p9;
    const void* idxk = L16 ? p12 : p10;
    const void* pmv  = L16 ? p13 : p11;
    const void* nint = L16 ? p14 : p12;
    const void* nimv = L16 ? p15 : p13;

    // ---- pmask register prefetch ----
    float pmr[8];
    {
        size_t pb = (size_t)(b * NA_ + a) * (NJ * NK);
#pragma unroll
        for (int s = 0; s < 8; ++s) {
            int tt = tid + s * 320;
            if (tt < NJ * NK) pmr[s] = ldf(pmv, pb + tt, pmF);
        }
    }

    float C[9];
#pragma unroll
    for (int i = 0; i < 9; ++i) C[i] = ldf(cellw, b * 9 + i, cF);
    const float ix = ldf(pos, (b * NA_ + a) * 3 + 0, pF);
    const float iy = ldf(pos, (b * NA_ + a) * 3 + 1, pF);
    const float iz = ldf(pos, (b * NA_ + a) * 3 + 2, pF);

    // ---- Phase A ----
    if (tid < NJ) {                          // wave 0: j geometry
        int j = tid;
        int id = ld_idx(idxj, (b * NA_ + a) * NJ + j, w64);
        id = min(max(id, 0), NA_ - 1);
        size_t ob = (size_t)((b * NA_ + a) * NJ + j) * 3;
        float o0 = bf2f(noi[ob]), o1 = bf2f(noi[ob + 1]), o2 = bf2f(noi[ob + 2]);
        float jx = ldf(pos, (b * NA_ + id) * 3 + 0, pF) + o0 * C[0] + o1 * C[3] + o2 * C[6];
        float jy = ldf(pos, (b * NA_ + id) * 3 + 1, pF) + o0 * C[1] + o1 * C[4] + o2 * C[7];
        float jz = ldf(pos, (b * NA_ + id) * 3 + 2, pF) + o0 * C[2] + o1 * C[5] + o2 * C[8];
        float dx = jx - ix, dy = jy - iy, dz = jz - iz;
        float rij2 = fmaxf(dx * dx + dy * dy + dz * dz, 1e-12f);
        float rij = sqrtf(rij2);
        sj[j * 6 + 0] = jx; sj[j * 6 + 1] = jy; sj[j * 6 + 2] = jz;
        sj[j * 6 + 3] = rij2; sj[j * 6 + 4] = 0.5f / rij; sj[j * 6 + 5] = cut8(rij);
    }
    if (tid >= 64 && tid < 64 + NK) {        // wave 1 lanes 0-39: k geometry
        int k = tid - 64;
        int id = ld_idx(idxk, (b * NA_ + a) * NK + k, w64);
        id = min(max(id, 0), NA_ - 1);
        size_t ob = (size_t)((b * NA_ + a) * NK + k) * 3;
        float o0 = bf2f(coi[ob]), o1 = bf2f(coi[ob + 1]), o2 = bf2f(coi[ob + 2]);
        float kx = ldf(pos, (b * NA_ + id) * 3 + 0, pF) + o0 * C[0] + o1 * C[3] + o2 * C[6];
        float ky = ldf(pos, (b * NA_ + id) * 3 + 1, pF) + o0 * C[1] + o1 * C[4] + o2 * C[7];
        float kz = ldf(pos, (b * NA_ + id) * 3 + 2, pF) + o0 * C[2] + o1 * C[5] + o2 * C[8];
        float dx = kx - ix, dy = ky - iy, dz = kz - iz;
        float rik2 = fmaxf(dx * dx + dy * dy + dz * dz, 1e-12f);
        float rik = sqrtf(rik2);
        sk[k * 6 + 0] = kx; sk[k * 6 + 1] = ky; sk[k * 6 + 2] = kz;
        sk[k * 6 + 3] = rik2; sk[k * 6 + 4] = 1.0f / rik; sk[k * 6 + 5] = cut8(rik);
    }
    if (wzi == 2) {                          // wave 2: classes + ballot-rank + scg2
        int cls = 9;
        if (lane < NK) {
            int k = lane;
            int id = ld_idx(idxk, (b * NA_ + a) * NK + k, w64);
            id = min(max(id, 0), NA_ - 1);
            int zi = ld_idx(Zv, b * NA_ + id, w64);
            zi = min(max(zi, 0), 9);
            float z0 = ldf(zww, zi * 5 + 0, zF), z1 = ldf(zww, zi * 5 + 1, zF);
            float z2 = ldf(zww, zi * 5 + 2, zF), z3 = ldf(zww, zi * 5 + 3, zF);
            float z4 = ldf(zww, zi * 5 + 4, zF);
            cls = (z0 != 0.0f) ? 0 : ((z1 != 0.0f) ? 1 : ((z2 != 0.0f) ? 2 :
                  ((z3 != 0.0f) ? 3 : ((z4 != 0.0f) ? 4 : 5))));
            szval[k] = z0 + z1 + z2 + z3 + z4;
        }
        // ballot-rank (no LDS dependency, no barrier)
        int pre = 0;
        u64 mybal = 0;
        int cnts[6];
#pragma unroll
        for (int c = 0; c < 6; ++c) {
            u64 blc = __ballot(cls == c);
            cnts[c] = __popcll(blc);
            pre += (c < cls) ? cnts[c] : 0;
            mybal = (c == cls) ? blc : mybal;
        }
        if (lane < NK) {
            u64 ltm = (1ull << lane) - 1ull;
            srnk[lane] = pre + __popcll(mybal & ltm);
        }
        if (lane < 6) {
            int cnt = 0;
#pragma unroll
            for (int c2 = 0; c2 < 5; ++c2) cnt += (c2 < lane) ? cnts[c2] : 0;
            sbnd[lane] = cnt;
        }
        if (lane >= 40 && lane < 40 + NAP) {
            float og = -1.0f + 0.1f * (float)(lane - 40);
            scg2[lane - 40] = FAST_EXP2(-36.06737602222409f * og * og);
        }
    }
    if (tid >= 201) {                        // waves 3-4: radial staging
        int n = tid - 201;
        int id = ld_idx(nbrv, (b * NA_ + a) * NNEI + n, w64);
        id = min(max(id, 0), NA_ - 1);
        size_t ob = (size_t)((b * NA_ + a) * NNEI + n) * 3;
        float o0 = bf2f(coff[ob]), o1 = bf2f(coff[ob + 1]), o2 = bf2f(coff[ob + 2]);
        float vx = ldf(pos, (b * NA_ + id) * 3 + 0, pF) + o0 * C[0] + o1 * C[3] + o2 * C[6] - ix;
        float vy = ldf(pos, (b * NA_ + id) * 3 + 1, pF) + o0 * C[1] + o1 * C[4] + o2 * C[7] - iy;
        float vz = ldf(pos, (b * NA_ + id) * 3 + 2, pF) + o0 * C[2] + o1 * C[5] + o2 * C[8] - iz;
        float d = sqrtf(fmaxf(vx * vx + vy * vy + vz * vz, 1e-12f));
        float m = ldf(nmw, (b * NA_ + a) * NNEI + n, nmF);
        float dm = (m != 0.0f) ? d : 0.0f;
        float w = cut8(dm) * m;
        int zi = ld_idx(Zv, b * NA_ + id, w64);
        zi = min(max(zi, 0), 9);
        sd[n] = dm;
#pragma unroll
        for (int e = 0; e < 5; ++e) swzl[n * 5 + e] = w * ldf(zww, zi * 5 + e, zF);
    }
    // ---- dists on idle threads (tids 104-127, 60-63, 189-190) ----
    {
        int ji = -1;
        if (tid >= 104 && tid < 128) ji = tid - 104;
        else if (tid >= 60 && tid < 64) ji = tid - 36;
        else if (tid >= 189 && tid < 191) ji = tid - 161;
        if (ji >= 0) {
            const int ad = (a < NHALF) ? a : (a - NHALF);
            const int j = ((a < NHALF) ? 0 : 30) + ji;
            int id = ld_idx(nint, (b * NA_ + ad) * NJ + j, w64);
            id = min(max(id, 0), NA_ - 1);
            size_t ob = (size_t)((b * NA_ + ad) * NJ + j) * 3;
            float o0 = bf2f(noi[ob]), o1 = bf2f(noi[ob + 1]), o2 = bf2f(noi[ob + 2]);
            float cx = ldf(pos, (b * NA_ + ad) * 3 + 0, pF);
            float cy = ldf(pos, (b * NA_ + ad) * 3 + 1, pF);
            float cz = ldf(pos, (b * NA_ + ad) * 3 + 2, pF);
            float vx = ldf(pos, (b * NA_ + id) * 3 + 0, pF) + o0 * C[0] + o1 * C[3] + o2 * C[6] - cx;
            float vy = ldf(pos, (b * NA_ + id) * 3 + 1, pF) + o0 * C[1] + o1 * C[4] + o2 * C[7] - cy;
            float vz = ldf(pos, (b * NA_ + id) * 3 + 2, pF) + o0 * C[2] + o1 * C[5] + o2 * C[8] - cz;
            float d = sqrtf(fmaxf(vx * vx + vy * vy + vz * vz, 1e-12f));
            float m = ldf(nimv, (b * NA_ + ad) * NJ + j, niF);
            float pd = (m != 0.0f) ? d : 1.0f;
            float fc = (pd < 9.0f) ? 0.5f * (cosf(pd * 0.3490658503988659f) + 1.0f) : 0.0f;
            float v0 = pd * fc;
            float v1 = fc / pd;
            v0 = (v0 == v0) ? v0 : 0.0f;
            v1 = (v1 == v1) ? v1 : 0.0f;
            int w0i = OFF_D + ((b * NHALF + ad) * NJ + j) * 2;
            if (w0i >= OFF_D && w0i + 1 < OFF_END) {
                out[w0i + 0] = v0;
                out[w0i + 1] = v1;
            }
            if (ji == 0 && b == 0 && a == 0 && armed)
                out[OFF_D] = ldexpf(1.0f + (float)mbits / 256.0f, 30 + ebits);
        }
    }
    __syncthreads();   // bar1

    // ---- Phase B: bf16-packed E/S at SORTED positions ----
    {
#pragma unroll
        for (int s = 0; s < 8; ++s) {
            int tt = tid + s * 320;
            if (tt < NJ * NK) {
                int j = tt / NK, k = tt - j * NK;
                float jx = sj[j * 6 + 0], jy = sj[j * 6 + 1], jz = sj[j * 6 + 2];
                float rij2 = sj[j * 6 + 3], aj = sj[j * 6 + 4], fcj = sj[j * 6 + 5];
                float kx = sk[k * 6 + 0], ky = sk[k * 6 + 1], kz = sk[k * 6 + 2];
                float rik2 = sk[k * 6 + 3], inv = sk[k * 6 + 4], fck = sk[k * 6 + 5];
                float ddx = kx - jx, ddy = ky - jy, ddz = kz - jz;
                float rjk2 = fmaxf(ddx * ddx + ddy * ddy + ddz * ddz, 1e-12f);
                float cth = (rij2 + rik2 - rjk2) * aj * inv;
                cth = fminf(fmaxf(cth, -1.0f), 1.0f);
                float wb = fcj * fck * pmr[s] * szval[k];
                float t0 = -36.06737602222409f * cth * cth;
                float E = FAST_EXP2(7.213475204444817f * cth);
                float S = wb * FAST_EXP2(t0 - 72.13475204444817f * cth);
                int rnk = srnk[k];
                U.scES[j * 41 + rnk] = (__float_as_uint(S) & 0xFFFF0000u) |
                                       (__float_as_uint(E) >> 16);
            }
        }
    }
    __syncthreads();   // bar2

    // ---- Phase C: linear chained accumulation (1 LDS read per k) ----
    float acc[5][5];
#pragma unroll
    for (int c = 0; c < 5; ++c)
#pragma unroll
        for (int t = 0; t < 5; ++t) acc[c][t] = 0.0f;
    const int gbase = wzi * 4;
    if (lane < NJ) {
        const int rowc = lane * 41;
#pragma unroll
        for (int c = 0; c < 5; ++c) {
            const int pend = sbnd[c + 1];
            for (int ppos = (c == 0) ? 0 : sbnd[c]; ppos < pend; ++ppos) {
                u32 pk = U.scES[rowc + ppos];
                float E = __uint_as_float(pk << 16);
                float S = __uint_as_float(pk & 0xFFFF0000u);
                float seed;
                if (wzi == 0) seed = S;
                else {
                    float E2 = E * E;
                    float E4 = E2 * E2;
                    if (wzi == 1) seed = S * E4;
                    else if (wzi == 2) seed = S * (E4 * E4);
                    else if (wzi == 3) seed = S * (E4 * E4) * E4;
                    else { float E8 = E4 * E4; seed = S * (E8 * E8); }
                }
                acc[c][0] += seed; seed *= E;
                acc[c][1] += seed; seed *= E;
                acc[c][2] += seed; seed *= E;
                acc[c][3] += seed; seed *= E;
                acc[c][4] += seed;
            }
        }
    }
    __syncthreads();   // bar3 (scES dead -> sacc16)

    if (lane < NJ) {
        float cgs[5];
#pragma unroll
        for (int t = 0; t < 5; ++t) cgs[t] = scg2[gbase + t];
        const int base = lane * 105;
#pragma unroll
        for (int c = 0; c < 5; ++c) {
#pragma unroll
            for (int t = 0; t < 5; ++t) {
                if (wzi == 0 || t > 0)
                    U.sacc16[base + c * 21 + gbase + t] =
                        (u16)(__float_as_uint(acc[c][t] * cgs[t]) >> 16);
            }
        }
    }
    __syncthreads();   // bar4

    // ---- coalesced AP copy (unpack bf16 -> float4) + concurrent radial partials ----
    {
        size_t ob2base = (a < NHALF)
            ? (size_t)OFF_APA + (size_t)(b * NHALF + a) * 6300
            : (size_t)OFF_APB + (size_t)(b * NHALF + (a - NHALF)) * 6300;
        for (int i4 = tid; i4 < 1575; i4 += 320) {
            size_t w = ob2base + (size_t)i4 * 4;
            if (w + 4 <= OFF_D) {
                u32 lo = U.sacc32[i4 * 2];
                u32 hi = U.sacc32[i4 * 2 + 1];
                float4 v;
                v.x = __uint_as_float(lo << 16);
                v.y = __uint_as_float(lo & 0xFFFF0000u);
                v.z = __uint_as_float(hi << 16);
                v.w = __uint_as_float(hi & 0xFFFF0000u);
                *(float4*)&out[w] = v;
            }
        }
    }
    if (tid < NRAD * 7) {   // radial partials (dpart separate: no union hazard)
        int r = tid / 7, s = tid - r * 7;
        float o = 0.8f + 0.1f * (float)r;
        float ac0 = 0.f, ac1 = 0.f, ac2 = 0.f, ac3 = 0.f, ac4 = 0.f;
        int n0 = s * 17;
        for (int n = n0; n < n0 + 17; ++n) {
            float dd = sd[n] - o;
            float q = FAST_EXP2(-144.26950408889635f * dd * dd);
            ac0 = fmaf(q, swzl[n * 5 + 0], ac0);
            ac1 = fmaf(q, swzl[n * 5 + 1], ac1);
            ac2 = fmaf(q, swzl[n * 5 + 2], ac2);
            ac3 = fmaf(q, swzl[n * 5 + 3], ac3);
            ac4 = fmaf(q, swzl[n * 5 + 4], ac4);
        }
        int pbase = (r * 7 + s) * 5;
        dpart[pbase + 0] = ac0; dpart[pbase + 1] = ac1; dpart[pbase + 2] = ac2;
        dpart[pbase + 3] = ac3; dpart[pbase + 4] = ac4;
    }
    __syncthreads();   // bar5

    if (tid < 5 * NRAD) {
        int e = tid / NRAD, r = tid - e * NRAD;
        float s7 = 0.f;
#pragma unroll
        for (int s = 0; s < 7; ++s) s7 += dpart[(r * 7 + s) * 5 + e];
        int base = (a < NHALF) ? (OFF_RA + (b * NHALF + a) * (5 * NRAD))
                               : (OFF_RB + (b * NHALF + (a - NHALF)) * (5 * NRAD));
        int widx = base + tid;
        if (widx < OFF_APA) out[widx] = s7;
    }
}

extern "C" void kernel_launch(void* const* d_in, const int* in_sizes, int n_in,
                              void* d_out, int out_size, void* d_ws, size_t ws_size,
                              hipStream_t stream) {
    const u16* pos   = (const u16*)d_in[0];
    const u16* cellw = (const u16*)d_in[1];
    const u16* coff  = (const u16*)d_in[2];
    const u16* noi   = (const u16*)d_in[3];
    const u16* coi   = (const u16*)d_in[4];
    const u16* zww   = (const u16*)d_in[5];
    const void* Zv   = d_in[6];
    const void* nbrv = d_in[7];
    const u16* nmw   = (const u16*)d_in[8];
    const void* p9  = d_in[9];
    const void* p10 = d_in[10];
    const void* p11 = d_in[11];
    const void* p12 = d_in[12];
    const void* p13 = d_in[13];
    const void* p14 = (n_in >= 15) ? d_in[14] : d_in[13];
    const void* p15 = (n_in >= 16) ? d_in[15] : d_in[13];
    float* out = (float*)d_out;

    k_fused<<<NB_ * NA_, 320, 0, stream>>>(pos, cellw, coff, noi, coi, zww, Zv,
                                           nbrv, nmw, p9, p10, p11, p12, p13,
                                           p14, p15, n_in, out);
}